// Round 3
// baseline (1737.437 us; speedup 1.0000x reference)
//
#include <hip/hip_runtime.h>

// ---------------------------------------------------------------------------
// LightGCN propagation: out = normalize(mean(emb, A emb, A^2 emb, A^3 emb))
// for two graphs (mashup: 100k nodes / 3.2M edges, api: 50k / 1.6M), D=64.
//
// Round-2:
//  - CSR build with TWO-PASS BUCKETED scatter (kills the 8x HBM write
//    amplification of random 8B scatters): pass1 appends (val,col)+row to
//    row-range buckets whose base = row_ptr[first_row_of_bucket] (so tmp is
//    positionally aligned with the final CSR array); pass2 re-reads
//    sequentially and places each edge at its exact slot -- destination now
//    falls in a ~16KB L2-resident window.
//  - SpMM gathers x in FP16 (fp32 accumulate), halving gather + inter-layer
//    traffic. acc+= and final normalize stay fused in the SpMM.
//  - fp16 buffers alias the scatter tmp region (ws ~65MB total).
// ---------------------------------------------------------------------------

#define EMB_DIM 64
#define RPB_SHIFT 6  // 64 rows per bucket
typedef unsigned long long ull;

static inline int cdiv(long long a, long long b) { return (int)((a + b - 1) / b); }

// ----------------------------- CSR build -----------------------------------

__global__ void k_zero_i(int* __restrict__ p, int n) {
    int i = blockIdx.x * blockDim.x + threadIdx.x;
    if (i < n) p[i] = 0;
}

__global__ void k_hist(const int* __restrict__ rows, int* __restrict__ counts,
                       int ne) {
    int i = blockIdx.x * blockDim.x + threadIdx.x;
    if (i < ne) atomicAdd(&counts[rows[i]], 1);
}

#define SCAN_B 256
#define SCAN_E 1024
__global__ void k_scan1(const int* __restrict__ in, int n,
                        int* __restrict__ out, int* __restrict__ bsums) {
    __shared__ int lds[SCAN_B];
    int t = threadIdx.x;
    int base = blockIdx.x * SCAN_E + t * 4;
    int v[4];
    int s = 0;
#pragma unroll
    for (int j = 0; j < 4; ++j) {
        v[j] = (base + j < n) ? in[base + j] : 0;
        s += v[j];
    }
    lds[t] = s;
    __syncthreads();
    for (int off = 1; off < SCAN_B; off <<= 1) {
        int x = (t >= off) ? lds[t - off] : 0;
        __syncthreads();
        lds[t] += x;
        __syncthreads();
    }
    int run = lds[t] - s;
    if (t == SCAN_B - 1) bsums[blockIdx.x] = lds[t];
#pragma unroll
    for (int j = 0; j < 4; ++j) {
        if (base + j < n) out[base + j] = run;
        run += v[j];
    }
}

__global__ void k_scan2(int* __restrict__ bsums, int nb) {
    __shared__ int lds[1024];
    int t = threadIdx.x;
    int v = (t < nb) ? bsums[t] : 0;
    lds[t] = v;
    __syncthreads();
    for (int off = 1; off < 1024; off <<= 1) {
        int x = (t >= off) ? lds[t - off] : 0;
        __syncthreads();
        lds[t] += x;
        __syncthreads();
    }
    if (t < nb) bsums[t] = lds[t] - v;
}

__global__ void k_scan3(int* __restrict__ row_ptr, int* __restrict__ row_pos,
                        const int* __restrict__ bsums, int n, int ne) {
    int i = blockIdx.x * blockDim.x + threadIdx.x;
    if (i < n) {
        int p = row_ptr[i] + bsums[i >> 10];
        row_ptr[i] = p;
        row_pos[i] = p;
    }
    if (i == 0) row_ptr[n] = ne;
}

// bucket_pos[b] = row_ptr[min(b<<RPB_SHIFT, n)]
__global__ void k_binit(const int* __restrict__ row_ptr,
                        int* __restrict__ bucket_pos, int n, int nb) {
    int b = blockIdx.x * blockDim.x + threadIdx.x;
    if (b <= nb) {
        int r = b << RPB_SHIFT;
        if (r > n) r = n;
        bucket_pos[b] = row_ptr[r];
    }
}

// pass 1: append to bucket streams (sequential write pointers per bucket).
__global__ void k_pass1(const int* __restrict__ rows,
                        const int* __restrict__ cols,
                        const float* __restrict__ vals, int ne,
                        int* __restrict__ bucket_pos,
                        ull* __restrict__ tmp_ev, int* __restrict__ tmp_row) {
    int i = blockIdx.x * blockDim.x + threadIdx.x;
    if (i < ne) {
        int r = rows[i];
        int p = atomicAdd(&bucket_pos[r >> RPB_SHIFT], 1);
        tmp_ev[p] = ((ull)__float_as_uint(vals[i]) << 32) | (unsigned)cols[i];
        tmp_row[p] = r;
    }
}

// pass 2: sequential read, short-range scatter to exact CSR slot.
__global__ void k_pass2(const ull* __restrict__ tmp_ev,
                        const int* __restrict__ tmp_row, int ne,
                        int* __restrict__ row_pos, ull* __restrict__ ev) {
    int i = blockIdx.x * blockDim.x + threadIdx.x;
    if (i < ne) {
        int r = tmp_row[i];
        int p = atomicAdd(&row_pos[r], 1);
        ev[p] = tmp_ev[i];
    }
}

// ----------------------------- fp16 convert --------------------------------

__global__ void k_tohalf(const float* __restrict__ s, _Float16* __restrict__ d,
                         int n) {
    int i = (blockIdx.x * blockDim.x + threadIdx.x) * 4;
    if (i < n) {
        float4 v = *reinterpret_cast<const float4*>(s + i);
        _Float16 h[4] = {(_Float16)v.x, (_Float16)v.y, (_Float16)v.z,
                         (_Float16)v.w};
        *reinterpret_cast<ushort4*>(d + i) = *reinterpret_cast<ushort4*>(h);
    }
}

// ----------------------------- CSR SpMM ------------------------------------
// One wave per row, lane = dim. sum = Σ val * x[col*64+lane]  (x is fp16).
//   FIRST:  acc = emb_row + sum ; nxt = (fp16)sum
//   middle: acc += sum          ; nxt = (fp16)sum
//   LAST:   a = (acc+sum)/4 ; normalize ; acc = a/||a||
template <bool FIRST, bool LAST>
__global__ void k_spmm_csr(const ull* __restrict__ ev,
                           const int* __restrict__ row_ptr,
                           const _Float16* __restrict__ x,
                           _Float16* __restrict__ nxt, float* __restrict__ acc,
                           const float* __restrict__ emb, int nrows) {
    int row = (int)((blockIdx.x * blockDim.x + threadIdx.x) >> 6);
    if (row >= nrows) return;
    int lane = threadIdx.x & 63;

    int s = row_ptr[row];
    int e = row_ptr[row + 1];

    float a0 = 0.f, a1 = 0.f, a2 = 0.f, a3 = 0.f;
    int j = s;
    for (; j + 4 <= e; j += 4) {
        ull p0 = ev[j], p1 = ev[j + 1], p2 = ev[j + 2], p3 = ev[j + 3];
        float x0 = (float)x[((size_t)(unsigned)p0 << 6) | lane];
        float x1 = (float)x[((size_t)(unsigned)p1 << 6) | lane];
        float x2 = (float)x[((size_t)(unsigned)p2 << 6) | lane];
        float x3 = (float)x[((size_t)(unsigned)p3 << 6) | lane];
        a0 = fmaf(__uint_as_float((unsigned)(p0 >> 32)), x0, a0);
        a1 = fmaf(__uint_as_float((unsigned)(p1 >> 32)), x1, a1);
        a2 = fmaf(__uint_as_float((unsigned)(p2 >> 32)), x2, a2);
        a3 = fmaf(__uint_as_float((unsigned)(p3 >> 32)), x3, a3);
    }
    for (; j < e; ++j) {
        ull p0 = ev[j];
        float x0 = (float)x[((size_t)(unsigned)p0 << 6) | lane];
        a0 = fmaf(__uint_as_float((unsigned)(p0 >> 32)), x0, a0);
    }
    float sum = (a0 + a1) + (a2 + a3);

    size_t idx = ((size_t)row << 6) | lane;
    if (FIRST) {
        acc[idx] = emb[idx] + sum;
        nxt[idx] = (_Float16)sum;
    } else if (!LAST) {
        acc[idx] += sum;
        nxt[idx] = (_Float16)sum;
    } else {
        float a = (acc[idx] + sum) * 0.25f;
        float ss = a * a;
#pragma unroll
        for (int off = 32; off; off >>= 1) ss += __shfl_xor(ss, off);
        float nrm = fmaxf(sqrtf(ss), 1e-12f);
        acc[idx] = a / nrm;
    }
}

// ----------------------- fallback: atomic path -----------------------------

__global__ void k_copy2(const float4* __restrict__ src, float4* __restrict__ a,
                        float4* __restrict__ b, int n4) {
    int i = blockIdx.x * blockDim.x + threadIdx.x;
    if (i < n4) {
        float4 v = src[i];
        a[i] = v;
        b[i] = v;
    }
}

__global__ void k_zero(float4* __restrict__ p, int n4) {
    int i = blockIdx.x * blockDim.x + threadIdx.x;
    if (i < n4) p[i] = make_float4(0.f, 0.f, 0.f, 0.f);
}

__global__ void k_axpy(float4* __restrict__ acc, const float4* __restrict__ x,
                       int n4) {
    int i = blockIdx.x * blockDim.x + threadIdx.x;
    if (i < n4) {
        float4 a = acc[i];
        float4 v = x[i];
        a.x += v.x; a.y += v.y; a.z += v.z; a.w += v.w;
        acc[i] = a;
    }
}

__global__ void k_spmm_atomic(const int* __restrict__ rows,
                              const int* __restrict__ cols,
                              const float* __restrict__ vals,
                              const float* __restrict__ x,
                              float* __restrict__ y, int n_edges) {
    unsigned tid = blockIdx.x * blockDim.x + threadIdx.x;
    unsigned e = tid >> 4;
    if (e >= (unsigned)n_edges) return;
    int sub = tid & 15;
    int r = rows[e];
    int c = cols[e];
    float v = vals[e];
    const float4 xv =
        *reinterpret_cast<const float4*>(x + ((size_t)c << 6) + (sub << 2));
    float* yp = y + ((size_t)r << 6) + (sub << 2);
    unsafeAtomicAdd(yp + 0, v * xv.x);
    unsafeAtomicAdd(yp + 1, v * xv.y);
    unsafeAtomicAdd(yp + 2, v * xv.z);
    unsafeAtomicAdd(yp + 3, v * xv.w);
}

__global__ void k_normalize(float* __restrict__ out, int nrows) {
    int row = blockIdx.x * 4 + (threadIdx.x >> 6);
    if (row >= nrows) return;
    int lane = threadIdx.x & 63;
    size_t idx = ((size_t)row << 6) + lane;
    float v = out[idx] * 0.25f;
    float s = v * v;
#pragma unroll
    for (int off = 32; off; off >>= 1) s += __shfl_xor(s, off);
    float norm = fmaxf(sqrtf(s), 1e-12f);
    out[idx] = v / norm;
}

// ---------------------------------------------------------------------------

extern "C" void kernel_launch(void* const* d_in, const int* in_sizes, int n_in,
                              void* d_out, int out_size, void* d_ws,
                              size_t ws_size, hipStream_t stream) {
    const int* m_rows = (const int*)d_in[0];
    const int* m_cols = (const int*)d_in[1];
    const float* m_vals = (const float*)d_in[2];
    const int* a_rows = (const int*)d_in[3];
    const int* a_cols = (const int*)d_in[4];
    const float* a_vals = (const float*)d_in[5];
    const float* m_emb = (const float*)d_in[6];
    const float* a_emb = (const float*)d_in[7];

    int ne_m = in_sizes[0];
    int ne_a = in_sizes[3];
    int nm = in_sizes[6] / EMB_DIM;
    int na = in_sizes[7] / EMB_DIM;

    size_t elems_m = (size_t)nm * EMB_DIM;
    float* out_m = (float*)d_out;
    float* out_a = out_m + elems_m;

    // ws layout (sized for the larger mashup graph; api pass reuses it).
    // T region is time-shared: {tmp_ev + tmp_row} during scatter, then
    // {x0h + buf0h} (fp16) during SpMM.
    char* w = (char*)d_ws;
    ull* ev = (ull*)w;              w += (size_t)ne_m * sizeof(ull);
    char* Treg = w;
    size_t t_scatter = (size_t)ne_m * (sizeof(ull) + sizeof(int));
    size_t t_spmm = 2 * elems_m * sizeof(_Float16);
    w += (t_scatter > t_spmm ? t_scatter : t_spmm);
    int* row_ptr = (int*)w;         w += ((size_t)nm + 1) * sizeof(int);
    int* row_pos = (int*)w;         w += (size_t)nm * sizeof(int);
    int* bucket_pos = (int*)w;      w += ((size_t)(nm >> RPB_SHIFT) + 2) * sizeof(int);
    int* bsums = (int*)w;           w += 1024 * sizeof(int);
    size_t need = (size_t)(w - (char*)d_ws);

    if (ws_size >= need) {
        ull* tmp_ev = (ull*)Treg;
        auto run_csr = [&](const int* rows, const int* cols, const float* vals,
                           const float* emb, float* out, int n, int ne) {
            int* tmp_row = (int*)(Treg + (size_t)ne * sizeof(ull));
            _Float16* x0h = (_Float16*)Treg;
            _Float16* buf0h = x0h + (size_t)n * EMB_DIM;
            int nb = n >> RPB_SHIFT;  // buckets 0..nb inclusive cover all rows

            // ---- CSR build ----
            k_zero_i<<<cdiv(n, 256), 256, 0, stream>>>(row_pos, n);
            k_hist<<<cdiv(ne, 256), 256, 0, stream>>>(rows, row_pos, ne);
            int nsb = cdiv(n, SCAN_E);
            k_scan1<<<nsb, SCAN_B, 0, stream>>>(row_pos, n, row_ptr, bsums);
            k_scan2<<<1, 1024, 0, stream>>>(bsums, nsb);
            k_scan3<<<cdiv(n, 256), 256, 0, stream>>>(row_ptr, row_pos, bsums,
                                                      n, ne);
            k_binit<<<cdiv(nb + 1, 256), 256, 0, stream>>>(row_ptr, bucket_pos,
                                                           n, nb);
            k_pass1<<<cdiv(ne, 256), 256, 0, stream>>>(rows, cols, vals, ne,
                                                       bucket_pos, tmp_ev,
                                                       tmp_row);
            k_pass2<<<cdiv(ne, 256), 256, 0, stream>>>(tmp_ev, tmp_row, ne,
                                                       row_pos, ev);
            // ---- fp16 source ----
            int nel = n * EMB_DIM;
            k_tohalf<<<cdiv(nel / 4, 256), 256, 0, stream>>>(emb, x0h, nel);
            // ---- 3 fused SpMM layers (fp16 ping-pong x0h <-> buf0h) ----
            int g = cdiv(n, 4);
            k_spmm_csr<true, false><<<g, 256, 0, stream>>>(
                ev, row_ptr, x0h, buf0h, out, emb, n);
            k_spmm_csr<false, false><<<g, 256, 0, stream>>>(
                ev, row_ptr, buf0h, x0h, out, nullptr, n);
            k_spmm_csr<false, true><<<g, 256, 0, stream>>>(
                ev, row_ptr, x0h, nullptr, out, nullptr, n);
        };
        run_csr(m_rows, m_cols, m_vals, m_emb, out_m, nm, ne_m);
        run_csr(a_rows, a_cols, a_vals, a_emb, out_a, na, ne_a);
        return;
    }

    // Fallback: round-0 atomic path.
    float* fb0 = (float*)d_ws;
    float* fb1 = fb0 + elems_m;
    auto run_atomic = [&](const int* rows, const int* cols, const float* vals,
                          const float* emb, float* out, int nrows,
                          int nedges) {
        size_t n = (size_t)nrows * EMB_DIM;
        int n4 = (int)(n / 4);
        int eg = cdiv(n4, 256);
        k_copy2<<<eg, 256, 0, stream>>>((const float4*)emb, (float4*)out,
                                        (float4*)fb0, n4);
        float* cur = fb0;
        float* nxt = fb1;
        int spmm_grid = cdiv((long long)nedges * 16, 256);
        for (int l = 0; l < 3; ++l) {
            k_zero<<<eg, 256, 0, stream>>>((float4*)nxt, n4);
            k_spmm_atomic<<<spmm_grid, 256, 0, stream>>>(rows, cols, vals, cur,
                                                         nxt, nedges);
            k_axpy<<<eg, 256, 0, stream>>>((float4*)out, (const float4*)nxt,
                                           n4);
            float* t = cur; cur = nxt; nxt = t;
        }
        k_normalize<<<cdiv(nrows, 4), 256, 0, stream>>>(out, nrows);
    };
    run_atomic(m_rows, m_cols, m_vals, m_emb, out_m, nm, ne_m);
    run_atomic(a_rows, a_cols, a_vals, a_emb, out_a, na, ne_a);
}

// Round 4
// 1040.671 us; speedup vs baseline: 1.6695x; 1.6695x over previous
//
#include <hip/hip_runtime.h>

// ---------------------------------------------------------------------------
// LightGCN propagation: out = normalize(mean(emb, A emb, A^2 emb, A^3 emb))
// for two graphs (mashup: 100k nodes / 3.2M edges, api: 50k / 1.6M), D=64.
//
// Round-3:
//  - Direct single-pass scatter (round-1 style; 100k-counter low contention)
//    with ILP-4: each thread runs 4 independent atomic->write chains.
//    (Round-2's bucketed two-pass scatter REGRESSED: 10x contention on 1563
//    counters + line fragmentation from cross-XCD appenders.)
//  - SpMM: one 64-lane wave per row, lane = dim, fp16 gather operand with
//    fp32 accumulate, UNROLL-8 (8 outstanding 128B LLC gathers per wave).
//    acc+= and final normalize fused into the SpMM dispatches.
// ---------------------------------------------------------------------------

#define EMB_DIM 64
typedef unsigned long long ull;

static inline int cdiv(long long a, long long b) { return (int)((a + b - 1) / b); }

// ----------------------------- CSR build -----------------------------------

__global__ void k_zero_i(int* __restrict__ p, int n) {
    int i = blockIdx.x * blockDim.x + threadIdx.x;
    if (i < n) p[i] = 0;
}

__global__ void k_hist(const int* __restrict__ rows, int* __restrict__ counts,
                       int ne) {
    int i = blockIdx.x * blockDim.x + threadIdx.x;
    if (i < ne) atomicAdd(&counts[rows[i]], 1);
}

#define SCAN_B 256
#define SCAN_E 1024
__global__ void k_scan1(const int* __restrict__ in, int n,
                        int* __restrict__ out, int* __restrict__ bsums) {
    __shared__ int lds[SCAN_B];
    int t = threadIdx.x;
    int base = blockIdx.x * SCAN_E + t * 4;
    int v[4];
    int s = 0;
#pragma unroll
    for (int j = 0; j < 4; ++j) {
        v[j] = (base + j < n) ? in[base + j] : 0;
        s += v[j];
    }
    lds[t] = s;
    __syncthreads();
    for (int off = 1; off < SCAN_B; off <<= 1) {
        int x = (t >= off) ? lds[t - off] : 0;
        __syncthreads();
        lds[t] += x;
        __syncthreads();
    }
    int run = lds[t] - s;
    if (t == SCAN_B - 1) bsums[blockIdx.x] = lds[t];
#pragma unroll
    for (int j = 0; j < 4; ++j) {
        if (base + j < n) out[base + j] = run;
        run += v[j];
    }
}

__global__ void k_scan2(int* __restrict__ bsums, int nb) {
    __shared__ int lds[1024];
    int t = threadIdx.x;
    int v = (t < nb) ? bsums[t] : 0;
    lds[t] = v;
    __syncthreads();
    for (int off = 1; off < 1024; off <<= 1) {
        int x = (t >= off) ? lds[t - off] : 0;
        __syncthreads();
        lds[t] += x;
        __syncthreads();
    }
    if (t < nb) bsums[t] = lds[t] - v;
}

__global__ void k_scan3(int* __restrict__ row_ptr, int* __restrict__ row_pos,
                        const int* __restrict__ bsums, int n, int ne) {
    int i = blockIdx.x * blockDim.x + threadIdx.x;
    if (i < n) {
        int p = row_ptr[i] + bsums[i >> 10];
        row_ptr[i] = p;
        row_pos[i] = p;
    }
    if (i == 0) row_ptr[n] = ne;
}

// Direct scatter, ILP-4: 4 independent atomic->write chains per thread.
__global__ void k_scatter(const int* __restrict__ rows,
                          const int* __restrict__ cols,
                          const float* __restrict__ vals, int ne,
                          int* __restrict__ row_pos, ull* __restrict__ ev) {
    int T = gridDim.x * blockDim.x;  // total threads; edges strided by T
    int i = blockIdx.x * blockDim.x + threadIdx.x;

    int idx[4], r[4];
    ull pk[4];
#pragma unroll
    for (int k = 0; k < 4; ++k) {
        idx[k] = i + k * T;
        if (idx[k] < ne) {
            r[k] = rows[idx[k]];
            pk[k] = ((ull)__float_as_uint(vals[idx[k]]) << 32) |
                    (unsigned)cols[idx[k]];
        }
    }
    int p[4];
#pragma unroll
    for (int k = 0; k < 4; ++k)
        if (idx[k] < ne) p[k] = atomicAdd(&row_pos[r[k]], 1);
#pragma unroll
    for (int k = 0; k < 4; ++k)
        if (idx[k] < ne) ev[p[k]] = pk[k];
}

// ----------------------------- fp16 convert --------------------------------

__global__ void k_tohalf(const float* __restrict__ s, _Float16* __restrict__ d,
                         int n) {
    int i = (blockIdx.x * blockDim.x + threadIdx.x) * 4;
    if (i < n) {
        float4 v = *reinterpret_cast<const float4*>(s + i);
        _Float16 h[4] = {(_Float16)v.x, (_Float16)v.y, (_Float16)v.z,
                         (_Float16)v.w};
        *reinterpret_cast<ushort4*>(d + i) = *reinterpret_cast<ushort4*>(h);
    }
}

// ----------------------------- CSR SpMM ------------------------------------
// One wave per row, lane = dim. sum = Σ val * x[col*64+lane]  (x is fp16).
// Unroll-8: 8 outstanding gathers per wave to cover LLC latency.
//   FIRST:  acc = emb_row + sum ; nxt = (fp16)sum
//   middle: acc += sum          ; nxt = (fp16)sum
//   LAST:   a = (acc+sum)/4 ; normalize ; acc = a/||a||
template <bool FIRST, bool LAST>
__global__ void k_spmm_csr(const ull* __restrict__ ev,
                           const int* __restrict__ row_ptr,
                           const _Float16* __restrict__ x,
                           _Float16* __restrict__ nxt, float* __restrict__ acc,
                           const float* __restrict__ emb, int nrows) {
    int row = (int)((blockIdx.x * blockDim.x + threadIdx.x) >> 6);
    if (row >= nrows) return;
    int lane = threadIdx.x & 63;

    int s = row_ptr[row];
    int e = row_ptr[row + 1];

    float a[8] = {0.f, 0.f, 0.f, 0.f, 0.f, 0.f, 0.f, 0.f};
    int j = s;
    for (; j + 8 <= e; j += 8) {
        ull p[8];
#pragma unroll
        for (int k = 0; k < 8; ++k) p[k] = ev[j + k];
#pragma unroll
        for (int k = 0; k < 8; ++k) {
            float xv = (float)x[((size_t)(unsigned)p[k] << 6) | lane];
            a[k] = fmaf(__uint_as_float((unsigned)(p[k] >> 32)), xv, a[k]);
        }
    }
    {
        // tail (< 8 edges), still overlapped
        ull p[8];
        int cnt = e - j;
#pragma unroll
        for (int k = 0; k < 8; ++k)
            if (k < cnt) p[k] = ev[j + k];
#pragma unroll
        for (int k = 0; k < 8; ++k)
            if (k < cnt) {
                float xv = (float)x[((size_t)(unsigned)p[k] << 6) | lane];
                a[k] = fmaf(__uint_as_float((unsigned)(p[k] >> 32)), xv, a[k]);
            }
    }
    float sum = ((a[0] + a[1]) + (a[2] + a[3])) + ((a[4] + a[5]) + (a[6] + a[7]));

    size_t idx = ((size_t)row << 6) | lane;
    if (FIRST) {
        acc[idx] = emb[idx] + sum;
        nxt[idx] = (_Float16)sum;
    } else if (!LAST) {
        acc[idx] += sum;
        nxt[idx] = (_Float16)sum;
    } else {
        float a_ = (acc[idx] + sum) * 0.25f;
        float ss = a_ * a_;
#pragma unroll
        for (int off = 32; off; off >>= 1) ss += __shfl_xor(ss, off);
        float nrm = fmaxf(sqrtf(ss), 1e-12f);
        acc[idx] = a_ / nrm;
    }
}

// ----------------------- fallback: atomic path -----------------------------

__global__ void k_copy2(const float4* __restrict__ src, float4* __restrict__ a,
                        float4* __restrict__ b, int n4) {
    int i = blockIdx.x * blockDim.x + threadIdx.x;
    if (i < n4) {
        float4 v = src[i];
        a[i] = v;
        b[i] = v;
    }
}

__global__ void k_zero(float4* __restrict__ p, int n4) {
    int i = blockIdx.x * blockDim.x + threadIdx.x;
    if (i < n4) p[i] = make_float4(0.f, 0.f, 0.f, 0.f);
}

__global__ void k_axpy(float4* __restrict__ acc, const float4* __restrict__ x,
                       int n4) {
    int i = blockIdx.x * blockDim.x + threadIdx.x;
    if (i < n4) {
        float4 a = acc[i];
        float4 v = x[i];
        a.x += v.x; a.y += v.y; a.z += v.z; a.w += v.w;
        acc[i] = a;
    }
}

__global__ void k_spmm_atomic(const int* __restrict__ rows,
                              const int* __restrict__ cols,
                              const float* __restrict__ vals,
                              const float* __restrict__ x,
                              float* __restrict__ y, int n_edges) {
    unsigned tid = blockIdx.x * blockDim.x + threadIdx.x;
    unsigned e = tid >> 4;
    if (e >= (unsigned)n_edges) return;
    int sub = tid & 15;
    int r = rows[e];
    int c = cols[e];
    float v = vals[e];
    const float4 xv =
        *reinterpret_cast<const float4*>(x + ((size_t)c << 6) + (sub << 2));
    float* yp = y + ((size_t)r << 6) + (sub << 2);
    unsafeAtomicAdd(yp + 0, v * xv.x);
    unsafeAtomicAdd(yp + 1, v * xv.y);
    unsafeAtomicAdd(yp + 2, v * xv.z);
    unsafeAtomicAdd(yp + 3, v * xv.w);
}

__global__ void k_normalize(float* __restrict__ out, int nrows) {
    int row = blockIdx.x * 4 + (threadIdx.x >> 6);
    if (row >= nrows) return;
    int lane = threadIdx.x & 63;
    size_t idx = ((size_t)row << 6) + lane;
    float v = out[idx] * 0.25f;
    float s = v * v;
#pragma unroll
    for (int off = 32; off; off >>= 1) s += __shfl_xor(s, off);
    float norm = fmaxf(sqrtf(s), 1e-12f);
    out[idx] = v / norm;
}

// ---------------------------------------------------------------------------

extern "C" void kernel_launch(void* const* d_in, const int* in_sizes, int n_in,
                              void* d_out, int out_size, void* d_ws,
                              size_t ws_size, hipStream_t stream) {
    const int* m_rows = (const int*)d_in[0];
    const int* m_cols = (const int*)d_in[1];
    const float* m_vals = (const float*)d_in[2];
    const int* a_rows = (const int*)d_in[3];
    const int* a_cols = (const int*)d_in[4];
    const float* a_vals = (const float*)d_in[5];
    const float* m_emb = (const float*)d_in[6];
    const float* a_emb = (const float*)d_in[7];

    int ne_m = in_sizes[0];
    int ne_a = in_sizes[3];
    int nm = in_sizes[6] / EMB_DIM;
    int na = in_sizes[7] / EMB_DIM;

    size_t elems_m = (size_t)nm * EMB_DIM;
    float* out_m = (float*)d_out;
    float* out_a = out_m + elems_m;

    // ws layout (sized for the larger mashup graph; api pass reuses it).
    char* w = (char*)d_ws;
    ull* ev = (ull*)w;              w += (size_t)ne_m * sizeof(ull);
    _Float16* x0h = (_Float16*)w;   w += elems_m * sizeof(_Float16);
    _Float16* buf0h = (_Float16*)w; w += elems_m * sizeof(_Float16);
    int* row_ptr = (int*)w;         w += ((size_t)nm + 1) * sizeof(int);
    int* row_pos = (int*)w;         w += (size_t)nm * sizeof(int);
    int* bsums = (int*)w;           w += 1024 * sizeof(int);
    size_t need = (size_t)(w - (char*)d_ws);

    if (ws_size >= need) {
        auto run_csr = [&](const int* rows, const int* cols, const float* vals,
                           const float* emb, float* out, int n, int ne) {
            // ---- CSR build ----
            k_zero_i<<<cdiv(n, 256), 256, 0, stream>>>(row_pos, n);
            k_hist<<<cdiv(ne, 256), 256, 0, stream>>>(rows, row_pos, ne);
            int nsb = cdiv(n, SCAN_E);
            k_scan1<<<nsb, SCAN_B, 0, stream>>>(row_pos, n, row_ptr, bsums);
            k_scan2<<<1, 1024, 0, stream>>>(bsums, nsb);
            k_scan3<<<cdiv(n, 256), 256, 0, stream>>>(row_ptr, row_pos, bsums,
                                                      n, ne);
            k_scatter<<<cdiv(ne, 256 * 4), 256, 0, stream>>>(rows, cols, vals,
                                                             ne, row_pos, ev);
            // ---- fp16 source ----
            int nel = n * EMB_DIM;
            k_tohalf<<<cdiv(nel / 4, 256), 256, 0, stream>>>(emb, x0h, nel);
            // ---- 3 fused SpMM layers (fp16 ping-pong x0h <-> buf0h) ----
            int g = cdiv(n, 4);
            k_spmm_csr<true, false><<<g, 256, 0, stream>>>(
                ev, row_ptr, x0h, buf0h, out, emb, n);
            k_spmm_csr<false, false><<<g, 256, 0, stream>>>(
                ev, row_ptr, buf0h, x0h, out, nullptr, n);
            k_spmm_csr<false, true><<<g, 256, 0, stream>>>(
                ev, row_ptr, x0h, nullptr, out, nullptr, n);
        };
        run_csr(m_rows, m_cols, m_vals, m_emb, out_m, nm, ne_m);
        run_csr(a_rows, a_cols, a_vals, a_emb, out_a, na, ne_a);
        return;
    }

    // Fallback: round-0 atomic path.
    float* fb0 = (float*)d_ws;
    float* fb1 = fb0 + elems_m;
    auto run_atomic = [&](const int* rows, const int* cols, const float* vals,
                          const float* emb, float* out, int nrows,
                          int nedges) {
        size_t n = (size_t)nrows * EMB_DIM;
        int n4 = (int)(n / 4);
        int eg = cdiv(n4, 256);
        k_copy2<<<eg, 256, 0, stream>>>((const float4*)emb, (float4*)out,
                                        (float4*)fb0, n4);
        float* cur = fb0;
        float* nxt = fb1;
        int spmm_grid = cdiv((long long)nedges * 16, 256);
        for (int l = 0; l < 3; ++l) {
            k_zero<<<eg, 256, 0, stream>>>((float4*)nxt, n4);
            k_spmm_atomic<<<spmm_grid, 256, 0, stream>>>(rows, cols, vals, cur,
                                                         nxt, nedges);
            k_axpy<<<eg, 256, 0, stream>>>((float4*)out, (const float4*)nxt,
                                           n4);
            float* t = cur; cur = nxt; nxt = t;
        }
        k_normalize<<<cdiv(nrows, 4), 256, 0, stream>>>(out, nrows);
    };
    run_atomic(m_rows, m_cols, m_vals, m_emb, out_m, nm, ne_m);
    run_atomic(a_rows, a_cols, a_vals, a_emb, out_a, na, ne_a);
}

// Round 5
// 1021.811 us; speedup vs baseline: 1.7004x; 1.0185x over previous
//
#include <hip/hip_runtime.h>

// ---------------------------------------------------------------------------
// LightGCN propagation: out = normalize(mean(emb, A emb, A^2 emb, A^3 emb))
// for two graphs (mashup: 100k nodes / 3.2M edges, api: 50k / 1.6M), D=64.
//
// Round-4:
//  - XCD-PARTITIONED scatter: rows split into 8 contiguous ranges; blocks
//    with blockIdx%8==p (round-robin block->XCD) filter the edge list (NT
//    loads) and write only partition p's CSR slots. All writers of an ev
//    line share one XCD's L2 -> lines merge before writeback (kills the 8x
//    WRITE_SIZE amplification seen in rounds 1-3).
//  - SpMM: wave-per-row, fp16 gather operand, fp32 accum, unroll-8; ev/acc/
//    emb streams use non-temporal loads so L2 keeps the gathered x rows.
// ---------------------------------------------------------------------------

#define EMB_DIM 64
typedef unsigned long long ull;
typedef int v4i __attribute__((ext_vector_type(4)));

static inline int cdiv(long long a, long long b) { return (int)((a + b - 1) / b); }

// ----------------------------- CSR build -----------------------------------

__global__ void k_zero_i(int* __restrict__ p, int n) {
    int i = blockIdx.x * blockDim.x + threadIdx.x;
    if (i < n) p[i] = 0;
}

__global__ void k_hist(const int* __restrict__ rows, int* __restrict__ counts,
                       int ne) {
    int i = blockIdx.x * blockDim.x + threadIdx.x;
    if (i < ne) atomicAdd(&counts[rows[i]], 1);
}

#define SCAN_B 256
#define SCAN_E 1024
__global__ void k_scan1(const int* __restrict__ in, int n,
                        int* __restrict__ out, int* __restrict__ bsums) {
    __shared__ int lds[SCAN_B];
    int t = threadIdx.x;
    int base = blockIdx.x * SCAN_E + t * 4;
    int v[4];
    int s = 0;
#pragma unroll
    for (int j = 0; j < 4; ++j) {
        v[j] = (base + j < n) ? in[base + j] : 0;
        s += v[j];
    }
    lds[t] = s;
    __syncthreads();
    for (int off = 1; off < SCAN_B; off <<= 1) {
        int x = (t >= off) ? lds[t - off] : 0;
        __syncthreads();
        lds[t] += x;
        __syncthreads();
    }
    int run = lds[t] - s;
    if (t == SCAN_B - 1) bsums[blockIdx.x] = lds[t];
#pragma unroll
    for (int j = 0; j < 4; ++j) {
        if (base + j < n) out[base + j] = run;
        run += v[j];
    }
}

__global__ void k_scan2(int* __restrict__ bsums, int nb) {
    __shared__ int lds[1024];
    int t = threadIdx.x;
    int v = (t < nb) ? bsums[t] : 0;
    lds[t] = v;
    __syncthreads();
    for (int off = 1; off < 1024; off <<= 1) {
        int x = (t >= off) ? lds[t - off] : 0;
        __syncthreads();
        lds[t] += x;
        __syncthreads();
    }
    if (t < nb) bsums[t] = lds[t] - v;
}

__global__ void k_scan3(int* __restrict__ row_ptr, int* __restrict__ row_pos,
                        const int* __restrict__ bsums, int n, int ne) {
    int i = blockIdx.x * blockDim.x + threadIdx.x;
    if (i < n) {
        int p = row_ptr[i] + bsums[i >> 10];
        row_ptr[i] = p;
        row_pos[i] = p;
    }
    if (i == 0) row_ptr[n] = ne;
}

// XCD-partitioned scatter. Partition p = (r*pmul)>>16 (8 contiguous row
// ranges). Blocks with blockIdx%8==p handle partition p: scan all edges with
// NT loads, emit only matching ones. All ev writes of partition p land in a
// ~3.2MB window owned by one XCD's L2 -> full-line merging before writeback.
__global__ void k_scatter_xcd(const int* __restrict__ rows,
                              const int* __restrict__ cols,
                              const float* __restrict__ vals, int ne,
                              unsigned pmul, int* __restrict__ row_pos,
                              ull* __restrict__ ev) {
    const int p = blockIdx.x & 7;
    const int bslot = blockIdx.x >> 3;
    const int nslot = gridDim.x >> 3;
    const int nb4 = ne >> 2;
    const v4i* rows4 = (const v4i*)rows;

    for (int g = bslot * blockDim.x + threadIdx.x; g < nb4;
         g += nslot * blockDim.x) {
        v4i r4 = __builtin_nontemporal_load(rows4 + g);
        int base = g << 2;
#pragma unroll
        for (int k = 0; k < 4; ++k) {
            int r = (k == 0) ? r4.x : (k == 1) ? r4.y : (k == 2) ? r4.z : r4.w;
            if ((int)(((unsigned)r * pmul) >> 16) == p) {
                int i = base + k;
                float v = __builtin_nontemporal_load(vals + i);
                int c = __builtin_nontemporal_load(cols + i);
                ull pk = ((ull)__float_as_uint(v) << 32) | (unsigned)c;
                int pos = atomicAdd(&row_pos[r], 1);
                ev[pos] = pk;
            }
        }
    }
    // tail (ne % 4 edges): one thread per partition scans them.
    if (bslot == 0 && threadIdx.x == 0) {
        for (int i = nb4 << 2; i < ne; ++i) {
            int r = rows[i];
            if ((int)(((unsigned)r * pmul) >> 16) == p) {
                ull pk = ((ull)__float_as_uint(vals[i]) << 32) |
                         (unsigned)cols[i];
                int pos = atomicAdd(&row_pos[r], 1);
                ev[pos] = pk;
            }
        }
    }
}

// ----------------------------- fp16 convert --------------------------------

__global__ void k_tohalf(const float* __restrict__ s, _Float16* __restrict__ d,
                         int n) {
    int i = (blockIdx.x * blockDim.x + threadIdx.x) * 4;
    if (i < n) {
        float4 v = *reinterpret_cast<const float4*>(s + i);
        _Float16 h[4] = {(_Float16)v.x, (_Float16)v.y, (_Float16)v.z,
                         (_Float16)v.w};
        *reinterpret_cast<ushort4*>(d + i) = *reinterpret_cast<ushort4*>(h);
    }
}

// ----------------------------- CSR SpMM ------------------------------------
// One wave per row, lane = dim. sum = Σ val * x[col*64+lane]  (x is fp16).
// Unroll-8 (8 outstanding gathers/wave). ev/acc/emb streamed with NT loads.
//   FIRST:  acc = emb_row + sum ; nxt = (fp16)sum
//   middle: acc += sum          ; nxt = (fp16)sum
//   LAST:   a = (acc+sum)/4 ; normalize ; acc = a/||a||
template <bool FIRST, bool LAST>
__global__ void k_spmm_csr(const ull* __restrict__ ev,
                           const int* __restrict__ row_ptr,
                           const _Float16* __restrict__ x,
                           _Float16* __restrict__ nxt, float* __restrict__ acc,
                           const float* __restrict__ emb, int nrows) {
    int row = (int)((blockIdx.x * blockDim.x + threadIdx.x) >> 6);
    if (row >= nrows) return;
    int lane = threadIdx.x & 63;

    int s = row_ptr[row];
    int e = row_ptr[row + 1];

    float a[8] = {0.f, 0.f, 0.f, 0.f, 0.f, 0.f, 0.f, 0.f};
    int j = s;
    for (; j + 8 <= e; j += 8) {
        ull p[8];
#pragma unroll
        for (int k = 0; k < 8; ++k) p[k] = __builtin_nontemporal_load(ev + j + k);
#pragma unroll
        for (int k = 0; k < 8; ++k) {
            float xv = (float)x[((size_t)(unsigned)p[k] << 6) | lane];
            a[k] = fmaf(__uint_as_float((unsigned)(p[k] >> 32)), xv, a[k]);
        }
    }
    {
        ull p[8];
        int cnt = e - j;
#pragma unroll
        for (int k = 0; k < 8; ++k)
            if (k < cnt) p[k] = __builtin_nontemporal_load(ev + j + k);
#pragma unroll
        for (int k = 0; k < 8; ++k)
            if (k < cnt) {
                float xv = (float)x[((size_t)(unsigned)p[k] << 6) | lane];
                a[k] = fmaf(__uint_as_float((unsigned)(p[k] >> 32)), xv, a[k]);
            }
    }
    float sum = ((a[0] + a[1]) + (a[2] + a[3])) + ((a[4] + a[5]) + (a[6] + a[7]));

    size_t idx = ((size_t)row << 6) | lane;
    if (FIRST) {
        float eb = __builtin_nontemporal_load(emb + idx);
        __builtin_nontemporal_store(eb + sum, acc + idx);
        nxt[idx] = (_Float16)sum;
    } else if (!LAST) {
        float ac = __builtin_nontemporal_load(acc + idx);
        __builtin_nontemporal_store(ac + sum, acc + idx);
        nxt[idx] = (_Float16)sum;
    } else {
        float ac = __builtin_nontemporal_load(acc + idx);
        float a_ = (ac + sum) * 0.25f;
        float ss = a_ * a_;
#pragma unroll
        for (int off = 32; off; off >>= 1) ss += __shfl_xor(ss, off);
        float nrm = fmaxf(sqrtf(ss), 1e-12f);
        __builtin_nontemporal_store(a_ / nrm, acc + idx);
    }
}

// ----------------------- fallback: atomic path -----------------------------

__global__ void k_copy2(const float4* __restrict__ src, float4* __restrict__ a,
                        float4* __restrict__ b, int n4) {
    int i = blockIdx.x * blockDim.x + threadIdx.x;
    if (i < n4) {
        float4 v = src[i];
        a[i] = v;
        b[i] = v;
    }
}

__global__ void k_zero(float4* __restrict__ p, int n4) {
    int i = blockIdx.x * blockDim.x + threadIdx.x;
    if (i < n4) p[i] = make_float4(0.f, 0.f, 0.f, 0.f);
}

__global__ void k_axpy(float4* __restrict__ acc, const float4* __restrict__ x,
                       int n4) {
    int i = blockIdx.x * blockDim.x + threadIdx.x;
    if (i < n4) {
        float4 a = acc[i];
        float4 v = x[i];
        a.x += v.x; a.y += v.y; a.z += v.z; a.w += v.w;
        acc[i] = a;
    }
}

__global__ void k_spmm_atomic(const int* __restrict__ rows,
                              const int* __restrict__ cols,
                              const float* __restrict__ vals,
                              const float* __restrict__ x,
                              float* __restrict__ y, int n_edges) {
    unsigned tid = blockIdx.x * blockDim.x + threadIdx.x;
    unsigned e = tid >> 4;
    if (e >= (unsigned)n_edges) return;
    int sub = tid & 15;
    int r = rows[e];
    int c = cols[e];
    float v = vals[e];
    const float4 xv =
        *reinterpret_cast<const float4*>(x + ((size_t)c << 6) + (sub << 2));
    float* yp = y + ((size_t)r << 6) + (sub << 2);
    unsafeAtomicAdd(yp + 0, v * xv.x);
    unsafeAtomicAdd(yp + 1, v * xv.y);
    unsafeAtomicAdd(yp + 2, v * xv.z);
    unsafeAtomicAdd(yp + 3, v * xv.w);
}

__global__ void k_normalize(float* __restrict__ out, int nrows) {
    int row = blockIdx.x * 4 + (threadIdx.x >> 6);
    if (row >= nrows) return;
    int lane = threadIdx.x & 63;
    size_t idx = ((size_t)row << 6) + lane;
    float v = out[idx] * 0.25f;
    float s = v * v;
#pragma unroll
    for (int off = 32; off; off >>= 1) s += __shfl_xor(s, off);
    float norm = fmaxf(sqrtf(s), 1e-12f);
    out[idx] = v / norm;
}

// ---------------------------------------------------------------------------

extern "C" void kernel_launch(void* const* d_in, const int* in_sizes, int n_in,
                              void* d_out, int out_size, void* d_ws,
                              size_t ws_size, hipStream_t stream) {
    const int* m_rows = (const int*)d_in[0];
    const int* m_cols = (const int*)d_in[1];
    const float* m_vals = (const float*)d_in[2];
    const int* a_rows = (const int*)d_in[3];
    const int* a_cols = (const int*)d_in[4];
    const float* a_vals = (const float*)d_in[5];
    const float* m_emb = (const float*)d_in[6];
    const float* a_emb = (const float*)d_in[7];

    int ne_m = in_sizes[0];
    int ne_a = in_sizes[3];
    int nm = in_sizes[6] / EMB_DIM;
    int na = in_sizes[7] / EMB_DIM;

    size_t elems_m = (size_t)nm * EMB_DIM;
    float* out_m = (float*)d_out;
    float* out_a = out_m + elems_m;

    // ws layout (sized for the larger mashup graph; api pass reuses it).
    char* w = (char*)d_ws;
    ull* ev = (ull*)w;              w += (size_t)ne_m * sizeof(ull);
    _Float16* x0h = (_Float16*)w;   w += elems_m * sizeof(_Float16);
    _Float16* buf0h = (_Float16*)w; w += elems_m * sizeof(_Float16);
    int* row_ptr = (int*)w;         w += ((size_t)nm + 1) * sizeof(int);
    int* row_pos = (int*)w;         w += (size_t)nm * sizeof(int);
    int* bsums = (int*)w;           w += 1024 * sizeof(int);
    size_t need = (size_t)(w - (char*)d_ws);

    if (ws_size >= need) {
        auto run_csr = [&](const int* rows, const int* cols, const float* vals,
                           const float* emb, float* out, int n, int ne) {
            // ---- CSR build ----
            k_zero_i<<<cdiv(n, 256), 256, 0, stream>>>(row_pos, n);
            k_hist<<<cdiv(ne, 256), 256, 0, stream>>>(rows, row_pos, ne);
            int nsb = cdiv(n, SCAN_E);
            k_scan1<<<nsb, SCAN_B, 0, stream>>>(row_pos, n, row_ptr, bsums);
            k_scan2<<<1, 1024, 0, stream>>>(bsums, nsb);
            k_scan3<<<cdiv(n, 256), 256, 0, stream>>>(row_ptr, row_pos, bsums,
                                                      n, ne);
            unsigned pmul = (unsigned)(((unsigned long long)8 << 16) /
                                       (unsigned)n);
            k_scatter_xcd<<<2048, 256, 0, stream>>>(rows, cols, vals, ne, pmul,
                                                    row_pos, ev);
            // ---- fp16 source ----
            int nel = n * EMB_DIM;
            k_tohalf<<<cdiv(nel / 4, 256), 256, 0, stream>>>(emb, x0h, nel);
            // ---- 3 fused SpMM layers (fp16 ping-pong x0h <-> buf0h) ----
            int g = cdiv(n, 4);
            k_spmm_csr<true, false><<<g, 256, 0, stream>>>(
                ev, row_ptr, x0h, buf0h, out, emb, n);
            k_spmm_csr<false, false><<<g, 256, 0, stream>>>(
                ev, row_ptr, buf0h, x0h, out, nullptr, n);
            k_spmm_csr<false, true><<<g, 256, 0, stream>>>(
                ev, row_ptr, x0h, nullptr, out, nullptr, n);
        };
        run_csr(m_rows, m_cols, m_vals, m_emb, out_m, nm, ne_m);
        run_csr(a_rows, a_cols, a_vals, a_emb, out_a, na, ne_a);
        return;
    }

    // Fallback: round-0 atomic path.
    float* fb0 = (float*)d_ws;
    float* fb1 = fb0 + elems_m;
    auto run_atomic = [&](const int* rows, const int* cols, const float* vals,
                          const float* emb, float* out, int nrows,
                          int nedges) {
        size_t n = (size_t)nrows * EMB_DIM;
        int n4 = (int)(n / 4);
        int eg = cdiv(n4, 256);
        k_copy2<<<eg, 256, 0, stream>>>((const float4*)emb, (float4*)out,
                                        (float4*)fb0, n4);
        float* cur = fb0;
        float* nxt = fb1;
        int spmm_grid = cdiv((long long)nedges * 16, 256);
        for (int l = 0; l < 3; ++l) {
            k_zero<<<eg, 256, 0, stream>>>((float4*)nxt, n4);
            k_spmm_atomic<<<spmm_grid, 256, 0, stream>>>(rows, cols, vals, cur,
                                                         nxt, nedges);
            k_axpy<<<eg, 256, 0, stream>>>((float4*)out, (const float4*)nxt,
                                           n4);
            float* t = cur; cur = nxt; nxt = t;
        }
        k_normalize<<<cdiv(nrows, 4), 256, 0, stream>>>(out, nrows);
    };
    run_atomic(m_rows, m_cols, m_vals, m_emb, out_m, nm, ne_m);
    run_atomic(a_rows, a_cols, a_vals, a_emb, out_a, na, ne_a);
}

// Round 6
// 960.973 us; speedup vs baseline: 1.8080x; 1.0633x over previous
//
#include <hip/hip_runtime.h>

// ---------------------------------------------------------------------------
// LightGCN propagation: out = normalize(mean(emb, A emb, A^2 emb, A^3 emb))
// for two graphs (mashup: 100k nodes / 3.2M edges, api: 50k / 1.6M), D=64.
//
// Round-5:
//  - DUAL-EDGE SpMM: lane = (half, sub); each half handles alternate edges,
//    gathering 2 fp16 dims per dword load -> 2 edges retired per load instr,
//    16 edges in flight per wave at unroll-8 (2x MLP vs round-4). Halves
//    combined via shfl_xor(32); normalize reduces over the 32-lane half.
//  - Merged CSR build: one zero + one vectorized hist + one scatter dispatch
//    covering both graphs (block ranges 1408/640 of a 2048-block grid keep
//    the blockIdx%8 -> XCD partition mapping co-resident).
//  - ev arrays for both graphs persist; fp16 ping-pong buffers are aliased
//    per-phase (ws ~65MB, under the proven >=78MB).
// ---------------------------------------------------------------------------

#define EMB_DIM 64
#define UNR 8
typedef unsigned long long ull;
typedef int v4i __attribute__((ext_vector_type(4)));

static inline int cdiv(long long a, long long b) { return (int)((a + b - 1) / b); }

// ----------------------------- CSR build -----------------------------------

__global__ void k_zero2(int* __restrict__ pm, int nm_, int* __restrict__ pa,
                        int na_) {
    int i = blockIdx.x * blockDim.x + threadIdx.x;
    if (i < nm_) pm[i] = 0;
    else if (i < nm_ + na_) pa[i - nm_] = 0;
}

// merged vectorized histogram: 4 edges per thread.
__global__ void k_hist2(const int* __restrict__ rm, int nem,
                        int* __restrict__ posm, const int* __restrict__ ra,
                        int nea, int* __restrict__ posa) {
    int nm4 = nem >> 2, na4 = nea >> 2;
    int i = blockIdx.x * blockDim.x + threadIdx.x;
    if (i < nm4) {
        v4i r = __builtin_nontemporal_load((const v4i*)rm + i);
        atomicAdd(&posm[r.x], 1);
        atomicAdd(&posm[r.y], 1);
        atomicAdd(&posm[r.z], 1);
        atomicAdd(&posm[r.w], 1);
    } else if (i < nm4 + na4) {
        v4i r = __builtin_nontemporal_load((const v4i*)ra + (i - nm4));
        atomicAdd(&posa[r.x], 1);
        atomicAdd(&posa[r.y], 1);
        atomicAdd(&posa[r.z], 1);
        atomicAdd(&posa[r.w], 1);
    } else if (i == nm4 + na4) {
        for (int t = nm4 << 2; t < nem; ++t) atomicAdd(&posm[rm[t]], 1);
        for (int t = na4 << 2; t < nea; ++t) atomicAdd(&posa[ra[t]], 1);
    }
}

#define SCAN_B 256
#define SCAN_E 1024
__global__ void k_scan1(const int* __restrict__ in, int n,
                        int* __restrict__ out, int* __restrict__ bsums) {
    __shared__ int lds[SCAN_B];
    int t = threadIdx.x;
    int base = blockIdx.x * SCAN_E + t * 4;
    int v[4];
    int s = 0;
#pragma unroll
    for (int j = 0; j < 4; ++j) {
        v[j] = (base + j < n) ? in[base + j] : 0;
        s += v[j];
    }
    lds[t] = s;
    __syncthreads();
    for (int off = 1; off < SCAN_B; off <<= 1) {
        int x = (t >= off) ? lds[t - off] : 0;
        __syncthreads();
        lds[t] += x;
        __syncthreads();
    }
    int run = lds[t] - s;
    if (t == SCAN_B - 1) bsums[blockIdx.x] = lds[t];
#pragma unroll
    for (int j = 0; j < 4; ++j) {
        if (base + j < n) out[base + j] = run;
        run += v[j];
    }
}

__global__ void k_scan2(int* __restrict__ bsums, int nb) {
    __shared__ int lds[1024];
    int t = threadIdx.x;
    int v = (t < nb) ? bsums[t] : 0;
    lds[t] = v;
    __syncthreads();
    for (int off = 1; off < 1024; off <<= 1) {
        int x = (t >= off) ? lds[t - off] : 0;
        __syncthreads();
        lds[t] += x;
        __syncthreads();
    }
    if (t < nb) bsums[t] = lds[t] - v;
}

__global__ void k_scan3(int* __restrict__ row_ptr, int* __restrict__ row_pos,
                        const int* __restrict__ bsums, int n, int ne) {
    int i = blockIdx.x * blockDim.x + threadIdx.x;
    if (i < n) {
        int p = row_ptr[i] + bsums[i >> 10];
        row_ptr[i] = p;
        row_pos[i] = p;
    }
    if (i == 0) row_ptr[n] = ne;
}

// Merged XCD-partitioned scatter: blocks [0,bm) -> mashup, [bm,grid) -> api
// (bm % 8 == 0 so blockIdx%8 keeps the partition meaning in both ranges).
__global__ void k_scatter2(const int* __restrict__ rm,
                           const int* __restrict__ cm,
                           const float* __restrict__ vm, int nem,
                           unsigned pmulm, int* __restrict__ posm,
                           ull* __restrict__ evm, const int* __restrict__ ra,
                           const int* __restrict__ ca,
                           const float* __restrict__ va, int nea,
                           unsigned pmula, int* __restrict__ posa,
                           ull* __restrict__ eva, int bm) {
    const int p = blockIdx.x & 7;
    const bool is_m = (int)blockIdx.x < bm;
    const int b = is_m ? blockIdx.x : blockIdx.x - bm;
    const int nslot = (is_m ? bm : (int)gridDim.x - bm) >> 3;
    const int bslot = b >> 3;

    const int* rows = is_m ? rm : ra;
    const int* cols = is_m ? cm : ca;
    const float* vals = is_m ? vm : va;
    const int ne = is_m ? nem : nea;
    const unsigned pmul = is_m ? pmulm : pmula;
    int* row_pos = is_m ? posm : posa;
    ull* ev = is_m ? evm : eva;

    const int nb4 = ne >> 2;
    const v4i* rows4 = (const v4i*)rows;

    for (int g = bslot * blockDim.x + threadIdx.x; g < nb4;
         g += nslot * blockDim.x) {
        v4i r4 = __builtin_nontemporal_load(rows4 + g);
        int base = g << 2;
#pragma unroll
        for (int k = 0; k < 4; ++k) {
            int r = (k == 0) ? r4.x : (k == 1) ? r4.y : (k == 2) ? r4.z : r4.w;
            if ((int)(((unsigned)r * pmul) >> 16) == p) {
                int i = base + k;
                float v = __builtin_nontemporal_load(vals + i);
                int c = __builtin_nontemporal_load(cols + i);
                ull pk = ((ull)__float_as_uint(v) << 32) | (unsigned)c;
                int pos = atomicAdd(&row_pos[r], 1);
                ev[pos] = pk;
            }
        }
    }
    if (bslot == 0 && threadIdx.x == 0) {
        for (int i = nb4 << 2; i < ne; ++i) {
            int r = rows[i];
            if ((int)(((unsigned)r * pmul) >> 16) == p) {
                ull pk = ((ull)__float_as_uint(vals[i]) << 32) |
                         (unsigned)cols[i];
                int pos = atomicAdd(&row_pos[r], 1);
                ev[pos] = pk;
            }
        }
    }
}

// ----------------------------- fp16 convert --------------------------------

__global__ void k_tohalf(const float* __restrict__ s, _Float16* __restrict__ d,
                         int n) {
    int i = (blockIdx.x * blockDim.x + threadIdx.x) * 4;
    if (i < n) {
        float4 v = *reinterpret_cast<const float4*>(s + i);
        _Float16 h[4] = {(_Float16)v.x, (_Float16)v.y, (_Float16)v.z,
                         (_Float16)v.w};
        *reinterpret_cast<ushort4*>(d + i) = *reinterpret_cast<ushort4*>(h);
    }
}

// ------------------------- dual-edge CSR SpMM ------------------------------
// One wave per row. lane = (h = lane>>5, sub = lane&31). Half h processes
// edges with slot%2==h; lane gathers dims (2sub, 2sub+1) as one dword.
// 2 edges per load instruction -> 16 edges in flight at UNR=8.
//   FIRST:  acc = emb_row + sum ; nxt = (fp16)sum
//   middle: acc += sum          ; nxt = (fp16)sum
//   LAST:   a = (acc+sum)/4 ; normalize ; acc = a/||a||
template <bool FIRST, bool LAST>
__global__ void k_spmm_dual(const ull* __restrict__ ev,
                            const int* __restrict__ row_ptr,
                            const _Float16* __restrict__ x,
                            _Float16* __restrict__ nxt,
                            float* __restrict__ acc,
                            const float* __restrict__ emb, int nrows) {
    int row = (int)((blockIdx.x * blockDim.x + threadIdx.x) >> 6);
    if (row >= nrows) return;
    int lane = threadIdx.x & 63;
    int h = lane >> 5;
    int sub = lane & 31;

    int s = row_ptr[row];
    int cnt = row_ptr[row + 1] - s;
    const ull* evr = ev + s;

    float ax[UNR], ay[UNR];
#pragma unroll
    for (int k = 0; k < UNR; ++k) { ax[k] = 0.f; ay[k] = 0.f; }

    int j = 0;
    for (; j + 2 * UNR <= cnt; j += 2 * UNR) {
        ull p[UNR];
#pragma unroll
        for (int k = 0; k < UNR; ++k)
            p[k] = __builtin_nontemporal_load(evr + j + 2 * k + h);
#pragma unroll
        for (int k = 0; k < UNR; ++k) {
            unsigned c = (unsigned)p[k];
            unsigned xd = *reinterpret_cast<const unsigned*>(
                x + ((size_t)c << 6) + (sub << 1));
            float v = __uint_as_float((unsigned)(p[k] >> 32));
            union { unsigned u; _Float16 f[2]; } cv;
            cv.u = xd;
            ax[k] = fmaf(v, (float)cv.f[0], ax[k]);
            ay[k] = fmaf(v, (float)cv.f[1], ay[k]);
        }
    }
    if (j < cnt) {
        ull p[UNR];
        bool act[UNR];
#pragma unroll
        for (int k = 0; k < UNR; ++k) {
            int slot = j + 2 * k + h;
            act[k] = slot < cnt;
            p[k] = act[k] ? __builtin_nontemporal_load(evr + slot) : 0ull;
        }
#pragma unroll
        for (int k = 0; k < UNR; ++k) {
            if (act[k]) {
                unsigned c = (unsigned)p[k];
                unsigned xd = *reinterpret_cast<const unsigned*>(
                    x + ((size_t)c << 6) + (sub << 1));
                float v = __uint_as_float((unsigned)(p[k] >> 32));
                union { unsigned u; _Float16 f[2]; } cv;
                cv.u = xd;
                ax[k] = fmaf(v, (float)cv.f[0], ax[k]);
                ay[k] = fmaf(v, (float)cv.f[1], ay[k]);
            }
        }
    }
    float tx = 0.f, ty = 0.f;
#pragma unroll
    for (int k = 0; k < UNR; ++k) { tx += ax[k]; ty += ay[k]; }
    tx += __shfl_xor(tx, 32);
    ty += __shfl_xor(ty, 32);
    // every lane now holds the full row sums for dims (2sub, 2sub+1)

    size_t base = ((size_t)row << 6) + (sub << 1);
    if (FIRST) {
        if (h == 0) {
            float2 e2 = *reinterpret_cast<const float2*>(emb + base);
            float2 o2 = make_float2(e2.x + tx, e2.y + ty);
            *reinterpret_cast<float2*>(acc + base) = o2;
            union { _Float16 f[2]; unsigned u; } o;
            o.f[0] = (_Float16)tx;
            o.f[1] = (_Float16)ty;
            *reinterpret_cast<unsigned*>(nxt + base) = o.u;
        }
    } else if (!LAST) {
        if (h == 0) {
            float2 a2 = *reinterpret_cast<const float2*>(acc + base);
            a2.x += tx;
            a2.y += ty;
            *reinterpret_cast<float2*>(acc + base) = a2;
            union { _Float16 f[2]; unsigned u; } o;
            o.f[0] = (_Float16)tx;
            o.f[1] = (_Float16)ty;
            *reinterpret_cast<unsigned*>(nxt + base) = o.u;
        }
    } else {
        float2 a2 = *reinterpret_cast<const float2*>(acc + base);
        float a0 = (a2.x + tx) * 0.25f;
        float a1 = (a2.y + ty) * 0.25f;
        float ss = a0 * a0 + a1 * a1;
#pragma unroll
        for (int off = 16; off; off >>= 1) ss += __shfl_xor(ss, off);
        float nrm = fmaxf(sqrtf(ss), 1e-12f);
        if (h == 0) {
            float2 o2 = make_float2(a0 / nrm, a1 / nrm);
            *reinterpret_cast<float2*>(acc + base) = o2;
        }
    }
}

// ----------------------- fallback: atomic path -----------------------------

__global__ void k_copy2(const float4* __restrict__ src, float4* __restrict__ a,
                        float4* __restrict__ b, int n4) {
    int i = blockIdx.x * blockDim.x + threadIdx.x;
    if (i < n4) {
        float4 v = src[i];
        a[i] = v;
        b[i] = v;
    }
}

__global__ void k_zero(float4* __restrict__ p, int n4) {
    int i = blockIdx.x * blockDim.x + threadIdx.x;
    if (i < n4) p[i] = make_float4(0.f, 0.f, 0.f, 0.f);
}

__global__ void k_axpy(float4* __restrict__ acc, const float4* __restrict__ x,
                       int n4) {
    int i = blockIdx.x * blockDim.x + threadIdx.x;
    if (i < n4) {
        float4 a = acc[i];
        float4 v = x[i];
        a.x += v.x; a.y += v.y; a.z += v.z; a.w += v.w;
        acc[i] = a;
    }
}

__global__ void k_spmm_atomic(const int* __restrict__ rows,
                              const int* __restrict__ cols,
                              const float* __restrict__ vals,
                              const float* __restrict__ x,
                              float* __restrict__ y, int n_edges) {
    unsigned tid = blockIdx.x * blockDim.x + threadIdx.x;
    unsigned e = tid >> 4;
    if (e >= (unsigned)n_edges) return;
    int sub = tid & 15;
    int r = rows[e];
    int c = cols[e];
    float v = vals[e];
    const float4 xv =
        *reinterpret_cast<const float4*>(x + ((size_t)c << 6) + (sub << 2));
    float* yp = y + ((size_t)r << 6) + (sub << 2);
    unsafeAtomicAdd(yp + 0, v * xv.x);
    unsafeAtomicAdd(yp + 1, v * xv.y);
    unsafeAtomicAdd(yp + 2, v * xv.z);
    unsafeAtomicAdd(yp + 3, v * xv.w);
}

__global__ void k_normalize(float* __restrict__ out, int nrows) {
    int row = blockIdx.x * 4 + (threadIdx.x >> 6);
    if (row >= nrows) return;
    int lane = threadIdx.x & 63;
    size_t idx = ((size_t)row << 6) + lane;
    float v = out[idx] * 0.25f;
    float s = v * v;
#pragma unroll
    for (int off = 32; off; off >>= 1) s += __shfl_xor(s, off);
    float norm = fmaxf(sqrtf(s), 1e-12f);
    out[idx] = v / norm;
}

// ---------------------------------------------------------------------------

extern "C" void kernel_launch(void* const* d_in, const int* in_sizes, int n_in,
                              void* d_out, int out_size, void* d_ws,
                              size_t ws_size, hipStream_t stream) {
    const int* m_rows = (const int*)d_in[0];
    const int* m_cols = (const int*)d_in[1];
    const float* m_vals = (const float*)d_in[2];
    const int* a_rows = (const int*)d_in[3];
    const int* a_cols = (const int*)d_in[4];
    const float* a_vals = (const float*)d_in[5];
    const float* m_emb = (const float*)d_in[6];
    const float* a_emb = (const float*)d_in[7];

    int ne_m = in_sizes[0];
    int ne_a = in_sizes[3];
    int nm = in_sizes[6] / EMB_DIM;
    int na = in_sizes[7] / EMB_DIM;

    size_t elems_m = (size_t)nm * EMB_DIM;
    int nmax = nm > na ? nm : na;
    float* out_m = (float*)d_out;
    float* out_a = out_m + elems_m;

    // ws layout: both ev arrays resident; fp16 buffers aliased per phase.
    char* w = (char*)d_ws;
    ull* ev_m = (ull*)w;            w += (size_t)ne_m * sizeof(ull);
    ull* ev_a = (ull*)w;            w += (size_t)ne_a * sizeof(ull);
    _Float16* x0h = (_Float16*)w;   w += (size_t)nmax * EMB_DIM * sizeof(_Float16);
    _Float16* buf0h = (_Float16*)w; w += (size_t)nmax * EMB_DIM * sizeof(_Float16);
    int* row_ptr_m = (int*)w;       w += ((size_t)nm + 1) * sizeof(int);
    int* row_pos_m = (int*)w;       w += (size_t)nm * sizeof(int);
    int* row_ptr_a = (int*)w;       w += ((size_t)na + 1) * sizeof(int);
    int* row_pos_a = (int*)w;       w += (size_t)na * sizeof(int);
    int* bsums = (int*)w;           w += 1024 * sizeof(int);
    size_t need = (size_t)(w - (char*)d_ws);

    if (ws_size >= need) {
        // ---- merged CSR build ----
        k_zero2<<<cdiv(nm + na, 256), 256, 0, stream>>>(row_pos_m, nm,
                                                        row_pos_a, na);
        k_hist2<<<cdiv((ne_m >> 2) + (ne_a >> 2) + 1, 256), 256, 0, stream>>>(
            m_rows, ne_m, row_pos_m, a_rows, ne_a, row_pos_a);
        int nsb_m = cdiv(nm, SCAN_E);
        k_scan1<<<nsb_m, SCAN_B, 0, stream>>>(row_pos_m, nm, row_ptr_m, bsums);
        k_scan2<<<1, 1024, 0, stream>>>(bsums, nsb_m);
        k_scan3<<<cdiv(nm, 256), 256, 0, stream>>>(row_ptr_m, row_pos_m, bsums,
                                                   nm, ne_m);
        int nsb_a = cdiv(na, SCAN_E);
        k_scan1<<<nsb_a, SCAN_B, 0, stream>>>(row_pos_a, na, row_ptr_a, bsums);
        k_scan2<<<1, 1024, 0, stream>>>(bsums, nsb_a);
        k_scan3<<<cdiv(na, 256), 256, 0, stream>>>(row_ptr_a, row_pos_a, bsums,
                                                   na, ne_a);
        unsigned pmul_m = (unsigned)(((unsigned long long)8 << 16) / (unsigned)nm);
        unsigned pmul_a = (unsigned)(((unsigned long long)8 << 16) / (unsigned)na);
        k_scatter2<<<2048, 256, 0, stream>>>(m_rows, m_cols, m_vals, ne_m,
                                             pmul_m, row_pos_m, ev_m, a_rows,
                                             a_cols, a_vals, ne_a, pmul_a,
                                             row_pos_a, ev_a, 1408);

        auto run_spmm = [&](ull* ev, int* row_ptr, const float* emb,
                            float* out, int n) {
            int nel = n * EMB_DIM;
            k_tohalf<<<cdiv(nel / 4, 256), 256, 0, stream>>>(emb, x0h, nel);
            int g = cdiv(n, 4);
            k_spmm_dual<true, false><<<g, 256, 0, stream>>>(
                ev, row_ptr, x0h, buf0h, out, emb, n);
            k_spmm_dual<false, false><<<g, 256, 0, stream>>>(
                ev, row_ptr, buf0h, x0h, out, nullptr, n);
            k_spmm_dual<false, true><<<g, 256, 0, stream>>>(
                ev, row_ptr, x0h, nullptr, out, nullptr, n);
        };
        run_spmm(ev_m, row_ptr_m, m_emb, out_m, nm);
        run_spmm(ev_a, row_ptr_a, a_emb, out_a, na);
        return;
    }

    // Fallback: round-0 atomic path.
    float* fb0 = (float*)d_ws;
    float* fb1 = fb0 + elems_m;
    auto run_atomic = [&](const int* rows, const int* cols, const float* vals,
                          const float* emb, float* out, int nrows,
                          int nedges) {
        size_t n = (size_t)nrows * EMB_DIM;
        int n4 = (int)(n / 4);
        int eg = cdiv(n4, 256);
        k_copy2<<<eg, 256, 0, stream>>>((const float4*)emb, (float4*)out,
                                        (float4*)fb0, n4);
        float* cur = fb0;
        float* nxt = fb1;
        int spmm_grid = cdiv((long long)nedges * 16, 256);
        for (int l = 0; l < 3; ++l) {
            k_zero<<<eg, 256, 0, stream>>>((float4*)nxt, n4);
            k_spmm_atomic<<<spmm_grid, 256, 0, stream>>>(rows, cols, vals, cur,
                                                         nxt, nedges);
            k_axpy<<<eg, 256, 0, stream>>>((float4*)out, (const float4*)nxt,
                                           n4);
            float* t = cur; cur = nxt; nxt = t;
        }
        k_normalize<<<cdiv(nrows, 4), 256, 0, stream>>>(out, nrows);
    };
    run_atomic(m_rows, m_cols, m_vals, m_emb, out_m, nm, ne_m);
    run_atomic(a_rows, a_cols, a_vals, a_emb, out_a, na, ne_a);
}